// Round 4
// baseline (1578.607 us; speedup 1.0000x reference)
//
#include <hip/hip_runtime.h>

constexpr int N_ENTITIES = 100000;
constexpr int N_USERS    = 50000;
constexpr int N_FACTORS  = 4;
constexpr int N_META     = 8;
constexpr int CHANNEL    = 64;
constexpr int N_EDGES    = 1600000;
constexpr int NNZ        = 1000000;
constexpr int N_REL      = 31;

constexpr int CB   = 196;    // coarse buckets (entities: 512 heads; users: 256 users)
constexpr int TILE = 8192;
constexpr int ETILES = (N_EDGES + TILE - 1) / TILE;  // 196
constexpr int NTILES = (NNZ + TILE - 1) / TILE;      // 123

// ws layout (ints): cnt_e@0(196) cnt_n@200(196) base_e@400(197) base_n@600(197)
//                   cur_e@800(196) cur_n@1000(196) pay_e@1280(1.6M) pay_n@1601280(2M)

__device__ __forceinline__ float wave_reduce_sum(float v) {
    for (int off = 32; off > 0; off >>= 1)
        v += __shfl_xor(v, off, 64);
    return v;
}

__global__ void count_kernel(const int* __restrict__ head,
                             const int* __restrict__ mat_row,
                             int* __restrict__ cnt_e, int* __restrict__ cnt_n) {
    __shared__ int he[CB], hn[CB];
    for (int i = threadIdx.x; i < CB; i += blockDim.x) { he[i] = 0; hn[i] = 0; }
    __syncthreads();
    const int i0 = blockIdx.x * blockDim.x + threadIdx.x;
    const int st = gridDim.x * blockDim.x;
    for (int e = i0; e < N_EDGES; e += st) atomicAdd(&he[head[e] >> 9], 1);
    for (int z = i0; z < NNZ;     z += st) atomicAdd(&hn[mat_row[z] >> 8], 1);
    __syncthreads();
    for (int i = threadIdx.x; i < CB; i += blockDim.x) {
        if (he[i]) atomicAdd(&cnt_e[i], he[i]);
        if (hn[i]) atomicAdd(&cnt_n[i], hn[i]);
    }
}

__global__ void scan_kernel(const int* __restrict__ cnt_e, const int* __restrict__ cnt_n,
                            int* __restrict__ base_e, int* __restrict__ base_n,
                            int* __restrict__ cur_e, int* __restrict__ cur_n) {
    if (threadIdx.x == 0) {
        int s = 0;
        for (int i = 0; i < CB; ++i) { base_e[i] = s; cur_e[i] = s; s += cnt_e[i]; }
        base_e[CB] = s;
    }
    if (threadIdx.x == 1) {
        int s = 0;
        for (int i = 0; i < CB; ++i) { base_n[i] = s; cur_n[i] = s; s += cnt_n[i]; }
        base_n[CB] = s;
    }
}

// Per-block range reservation: each block's per-bucket run is contiguous,
// written in one burst from one XCD -> L2 assembles full lines.
__global__ void scatter_kernel(const int* __restrict__ head,
                               const int* __restrict__ tail,
                               const int* __restrict__ etype,
                               const int* __restrict__ mat_row,
                               const int* __restrict__ mat_col,
                               const float* __restrict__ mat_val,
                               int* __restrict__ cur_e, int* __restrict__ cur_n,
                               int* __restrict__ pay_e, int2* __restrict__ pay_n) {
    __shared__ int hist[CB], bbase[CB], lcur[CB];
    const int tid = threadIdx.x;
    for (int i = tid; i < CB; i += blockDim.x) { hist[i] = 0; lcur[i] = 0; }
    __syncthreads();
    if (blockIdx.x < ETILES) {
        const int s = blockIdx.x * TILE, e = min(s + TILE, N_EDGES);
        for (int i = s + tid; i < e; i += blockDim.x) atomicAdd(&hist[head[i] >> 9], 1);
        __syncthreads();
        for (int b = tid; b < CB; b += blockDim.x)
            if (hist[b]) bbase[b] = atomicAdd(&cur_e[b], hist[b]);
        __syncthreads();
        for (int i = s + tid; i < e; i += blockDim.x) {
            const int h = head[i], b = h >> 9;
            const int pos = atomicAdd(&lcur[b], 1);
            pay_e[bbase[b] + pos] = ((h & 511) << 22) | ((etype[i] - 1) << 17) | tail[i];
        }
    } else {
        const int s = (blockIdx.x - ETILES) * TILE, e = min(s + TILE, NNZ);
        for (int i = s + tid; i < e; i += blockDim.x) atomicAdd(&hist[mat_row[i] >> 8], 1);
        __syncthreads();
        for (int b = tid; b < CB; b += blockDim.x)
            if (hist[b]) bbase[b] = atomicAdd(&cur_n[b], hist[b]);
        __syncthreads();
        for (int i = s + tid; i < e; i += blockDim.x) {
            const int r = mat_row[i], b = r >> 8;
            const int pos = atomicAdd(&lcur[b], 1);
            int2 p; p.x = ((r & 255) << 17) | mat_col[i]; p.y = __float_as_int(mat_val[i]);
            pay_n[bbase[b] + pos] = p;
        }
    }
}

// 784 blocks: block = (coarse bucket cb = bid/4, sub-window sub = bid%4 of 128 heads).
__global__ void ent_agg_kernel(const float* __restrict__ emb,
                               const float* __restrict__ rel_w,
                               const int* __restrict__ base_e,
                               const int* __restrict__ cnt_e,
                               const int* __restrict__ pay_e,
                               float* __restrict__ out_ent) {
    __shared__ float accum[128][CHANNEL];   // 32 KB
    __shared__ float att_s[128][N_REL];     // 15.5 KB
    __shared__ int   cnt_s[128];
    const int tid = threadIdx.x;
    const int cb  = blockIdx.x >> 2, sub = blockIdx.x & 3;
    const int h0  = cb * 512 + sub * 128;

    for (int i = tid; i < 128 * CHANNEL; i += 256) accum[i >> 6][i & 63] = 0.f;
    if (tid < 128) cnt_s[tid] = 0;
    // att[hl][r] = sigmoid(dot(emb[h0+hl], rel_w[r])) — each pair computed once
    for (int p = tid; p < 128 * 32; p += 256) {
        const int hl = p >> 5, r = p & 31;
        if (r < N_REL) {
            const int h = h0 + hl;
            float a = 0.f;
            if (h < N_ENTITIES) {
                for (int c = 0; c < CHANNEL; ++c)
                    a += emb[h * CHANNEL + c] * rel_w[r * CHANNEL + c];
                a = 1.f / (1.f + __expf(-a));
            }
            att_s[hl][r] = a;
        }
    }
    __syncthreads();

    const int lane = tid & 63, wib = tid >> 6;
    const int start = base_e[cb], end = start + cnt_e[cb];
    for (int i = start + wib * 64; i < end; i += 4 * 64) {
        const int idx = i + lane;
        const int pl = (idx < end) ? pay_e[idx] : 0;
        const bool mine = (idx < end) && (((pl >> 29) & 3) == sub);
        unsigned long long m = __ballot(mine);
        while (m) {
            const int b = __ffsll((long long)m) - 1; m &= m - 1;
            const int p  = __shfl(pl, b);
            const int hl = (p >> 22) & 127, r = (p >> 17) & 31, t = p & 0x1FFFF;
            const float contrib = att_s[hl][r] * rel_w[r * CHANNEL + lane] *
                                  emb[t * CHANNEL + lane];
            atomicAdd(&accum[hl][lane], contrib);
            if (lane == 0) atomicAdd(&cnt_s[hl], 1);
        }
    }
    __syncthreads();
    for (int hl = wib; hl < 128; hl += 4) {
        const int h = h0 + hl;
        if (h < N_ENTITIES)
            out_ent[h * CHANNEL + lane] = accum[hl][lane] / fmaxf((float)cnt_s[hl], 1.f);
    }
}

// 784 blocks: cb = bid/4 (256-user bucket), sub = bid%4 (64-user window).
__global__ void user_agg_kernel(const float* __restrict__ emb,
                                const float* __restrict__ user_emb,
                                const float* __restrict__ latent,
                                const float* __restrict__ weight,
                                const float* __restrict__ datt,
                                const int* __restrict__ base_n,
                                const int* __restrict__ cnt_n,
                                const int2* __restrict__ pay_n,
                                float* __restrict__ out_user) {
    __shared__ float accum[64][CHANNEL];      // 16 KB
    __shared__ float dw[N_FACTORS][CHANNEL];  // 1 KB
    const int tid = threadIdx.x;
    const int cb  = blockIdx.x >> 2, sub = blockIdx.x & 3;
    const int u0  = cb * 256 + sub * 64;

    for (int i = tid; i < 64 * CHANNEL; i += 256) accum[i >> 6][i & 63] = 0.f;
    {   // disen_weight = softmax(datt) @ weight, 4x64 by 256 threads
        const int f = tid >> 6, c = tid & 63;
        float mx = -1e30f;
        for (int j = 0; j < N_META; ++j) mx = fmaxf(mx, datt[f * N_META + j]);
        float p[N_META], s = 0.f;
        for (int j = 0; j < N_META; ++j) { p[j] = __expf(datt[f * N_META + j] - mx); s += p[j]; }
        float acc = 0.f;
        for (int j = 0; j < N_META; ++j) acc += p[j] * weight[j * CHANNEL + c];
        dw[f][c] = acc / s;
    }
    __syncthreads();

    const int lane = tid & 63, wib = tid >> 6;
    const int start = base_n[cb], end = start + cnt_n[cb];
    for (int i = start + wib * 64; i < end; i += 4 * 64) {
        const int idx = i + lane;
        int2 pl = make_int2(0, 0);
        if (idx < end) pl = pay_n[idx];
        const bool mine = (idx < end) && (((pl.x >> 23) & 3) == sub);
        unsigned long long m = __ballot(mine);
        while (m) {
            const int b = __ffsll((long long)m) - 1; m &= m - 1;
            const int w0 = __shfl(pl.x, b), w1 = __shfl(pl.y, b);
            const int ul = (w0 >> 17) & 63, c = w0 & 0x1FFFF;
            atomicAdd(&accum[ul][lane], __int_as_float(w1) * emb[c * CHANNEL + lane]);
        }
    }
    __syncthreads();
    for (int ul = wib; ul < 64; ul += 4) {
        const int u = u0 + ul;
        if (u < N_USERS) {
            const float ue = user_emb[u * CHANNEL + lane];
            float d0 = wave_reduce_sum(ue * latent[0 * CHANNEL + lane]);
            float d1 = wave_reduce_sum(ue * latent[1 * CHANNEL + lane]);
            float d2 = wave_reduce_sum(ue * latent[2 * CHANNEL + lane]);
            float d3 = wave_reduce_sum(ue * latent[3 * CHANNEL + lane]);
            const float mx = fmaxf(fmaxf(d0, d1), fmaxf(d2, d3));
            d0 = __expf(d0 - mx); d1 = __expf(d1 - mx);
            d2 = __expf(d2 - mx); d3 = __expf(d3 - mx);
            const float invs = 1.f / (d0 + d1 + d2 + d3);
            const float g = (d0 * dw[0][lane] + d1 * dw[1][lane] +
                             d2 * dw[2][lane] + d3 * dw[3][lane]) * invs;
            out_user[u * CHANNEL + lane] = accum[ul][lane] * (1.f + g);
        }
    }
}

extern "C" void kernel_launch(void* const* d_in, const int* in_sizes, int n_in,
                              void* d_out, int out_size, void* d_ws, size_t ws_size,
                              hipStream_t stream) {
    const float* entity_emb = (const float*)d_in[0];
    const float* user_emb   = (const float*)d_in[1];
    const float* latent_emb = (const float*)d_in[2];
    const int*   head       = (const int*)d_in[3];
    const int*   tail       = (const int*)d_in[4];
    const int*   etype      = (const int*)d_in[5];
    const int*   mat_row    = (const int*)d_in[6];
    const int*   mat_col    = (const int*)d_in[7];
    const float* mat_val    = (const float*)d_in[8];
    const float* rel_w      = (const float*)d_in[9];
    const float* weight     = (const float*)d_in[10];
    const float* datt       = (const float*)d_in[11];

    float* out      = (float*)d_out;
    float* out_ent  = out;                                  // N_ENTITIES*64
    float* out_user = out + (size_t)N_ENTITIES * CHANNEL;   // N_USERS*64

    int*  ws     = (int*)d_ws;
    int*  cnt_e  = ws;            // 196
    int*  cnt_n  = ws + 200;      // 196
    int*  base_e = ws + 400;      // 197
    int*  base_n = ws + 600;      // 197
    int*  cur_e  = ws + 800;      // 196
    int*  cur_n  = ws + 1000;     // 196
    int*  pay_e  = ws + 1280;     // 1.6M
    int2* pay_n  = (int2*)(ws + 1601280); // 1M int2

    hipMemsetAsync(ws, 0, 400 * sizeof(int), stream);  // cnt_e + cnt_n

    count_kernel<<<256, 256, 0, stream>>>(head, mat_row, cnt_e, cnt_n);
    scan_kernel<<<1, 64, 0, stream>>>(cnt_e, cnt_n, base_e, base_n, cur_e, cur_n);
    scatter_kernel<<<ETILES + NTILES, 256, 0, stream>>>(head, tail, etype,
                                                        mat_row, mat_col, mat_val,
                                                        cur_e, cur_n, pay_e, pay_n);
    ent_agg_kernel<<<784, 256, 0, stream>>>(entity_emb, rel_w, base_e, cnt_e,
                                            pay_e, out_ent);
    user_agg_kernel<<<784, 256, 0, stream>>>(entity_emb, user_emb, latent_emb,
                                             weight, datt, base_n, cnt_n,
                                             pay_n, out_user);
}

// Round 5
// 1430.979 us; speedup vs baseline: 1.1032x; 1.1032x over previous
//
#include <hip/hip_runtime.h>

constexpr int N_ENTITIES = 100000;
constexpr int N_USERS    = 50000;
constexpr int N_META     = 8;
constexpr int CHANNEL    = 64;
constexpr int N_EDGES    = 1600000;
constexpr int NNZ        = 1000000;
constexpr int N_REL      = 31;

constexpr int EB   = 128;                              // heads per entity bucket
constexpr int UB   = 128;                              // users per user bucket
constexpr int NB_E = (N_ENTITIES + EB - 1) / EB;       // 782
constexpr int NB_U = (N_USERS + UB - 1) / UB;          // 391
constexpr int TILE   = 8192;
constexpr int ETILES = (N_EDGES + TILE - 1) / TILE;    // 196
constexpr int NTILES = (NNZ + TILE - 1) / TILE;        // 123

// ws layout (ints): cntE@0(800) cntU@800(400) baseE@1200(800) baseU@2000(400)
//                   curE@2400(800) curU@3200(400) payE@3600(1.6M)
//                   payU@1603600(1M int2)  -> total 14.4 MB

__device__ __forceinline__ float wave_reduce_sum(float v) {
    for (int off = 32; off > 0; off >>= 1)
        v += __shfl_xor(v, off, 64);
    return v;
}

__global__ void count_kernel(const int* __restrict__ head,
                             const int* __restrict__ mat_row,
                             int* __restrict__ cntE, int* __restrict__ cntU) {
    __shared__ int he[NB_E], hu[NB_U];
    for (int i = threadIdx.x; i < NB_E; i += blockDim.x) he[i] = 0;
    for (int i = threadIdx.x; i < NB_U; i += blockDim.x) hu[i] = 0;
    __syncthreads();
    const int i0 = blockIdx.x * blockDim.x + threadIdx.x;
    const int st = gridDim.x * blockDim.x;
    for (int e = i0; e < N_EDGES; e += st) atomicAdd(&he[head[e] >> 7], 1);
    for (int z = i0; z < NNZ;     z += st) atomicAdd(&hu[mat_row[z] >> 7], 1);
    __syncthreads();
    for (int i = threadIdx.x; i < NB_E; i += blockDim.x)
        if (he[i]) atomicAdd(&cntE[i], he[i]);
    for (int i = threadIdx.x; i < NB_U; i += blockDim.x)
        if (hu[i]) atomicAdd(&cntU[i], hu[i]);
}

__device__ void block_scan(const int* cnt, int n, int* base, int* cur, int* arr) {
    const int t = threadIdx.x;
    const int own = (t < n) ? cnt[t] : 0;
    arr[t] = own;
    __syncthreads();
    for (int d = 1; d < 1024; d <<= 1) {
        int v = (t >= d) ? arr[t - d] : 0;
        __syncthreads();
        arr[t] += v;
        __syncthreads();
    }
    if (t < n) { const int e = arr[t] - own; base[t] = e; cur[t] = e; }
    if (t == 1023) base[n] = arr[1023];
    __syncthreads();
}

__global__ void scan_kernel(const int* cntE, const int* cntU,
                            int* baseE, int* curE, int* baseU, int* curU) {
    __shared__ int arr[1024];
    block_scan(cntE, NB_E, baseE, curE, arr);
    block_scan(cntU, NB_U, baseU, curU, arr);
}

// Per-block range reservation -> contiguous ~line-sized runs per bucket.
__global__ void scatter_kernel(const int* __restrict__ head,
                               const int* __restrict__ tail,
                               const int* __restrict__ etype,
                               const int* __restrict__ mat_row,
                               const int* __restrict__ mat_col,
                               const float* __restrict__ mat_val,
                               int* __restrict__ curE, int* __restrict__ curU,
                               int* __restrict__ payE, int2* __restrict__ payU) {
    __shared__ int hist[NB_E], bbase[NB_E], lcur[NB_E];
    const int tid = threadIdx.x;
    if (blockIdx.x < ETILES) {
        for (int i = tid; i < NB_E; i += blockDim.x) { hist[i] = 0; lcur[i] = 0; }
        __syncthreads();
        const int s = blockIdx.x * TILE, e = min(s + TILE, N_EDGES);
        for (int i = s + tid; i < e; i += blockDim.x) atomicAdd(&hist[head[i] >> 7], 1);
        __syncthreads();
        for (int b = tid; b < NB_E; b += blockDim.x)
            if (hist[b]) bbase[b] = atomicAdd(&curE[b], hist[b]);
        __syncthreads();
        for (int i = s + tid; i < e; i += blockDim.x) {
            const int h = head[i], b = h >> 7;
            const int pos = atomicAdd(&lcur[b], 1);
            payE[bbase[b] + pos] = ((h & 127) << 22) | ((etype[i] - 1) << 17) | tail[i];
        }
    } else {
        for (int i = tid; i < NB_U; i += blockDim.x) { hist[i] = 0; lcur[i] = 0; }
        __syncthreads();
        const int s = (blockIdx.x - ETILES) * TILE, e = min(s + TILE, NNZ);
        for (int i = s + tid; i < e; i += blockDim.x) atomicAdd(&hist[mat_row[i] >> 7], 1);
        __syncthreads();
        for (int b = tid; b < NB_U; b += blockDim.x)
            if (hist[b]) bbase[b] = atomicAdd(&curU[b], hist[b]);
        __syncthreads();
        for (int i = s + tid; i < e; i += blockDim.x) {
            const int r = mat_row[i], b = r >> 7;
            const int pos = atomicAdd(&lcur[b], 1);
            int2 p; p.x = ((r & 127) << 17) | mat_col[i]; p.y = __float_as_int(mat_val[i]);
            payU[bbase[b] + pos] = p;
        }
    }
}

// One block per 128-head bucket. Full accumulator tile in LDS -> every wave
// processes edges directly (lane = channel), no routing, no ballot.
__global__ __launch_bounds__(512) void ent_agg_kernel(
        const float* __restrict__ emb, const float* __restrict__ rel_w,
        const int* __restrict__ baseE, const int* __restrict__ payE,
        float* __restrict__ out_ent) {
    __shared__ float accum[EB][CHANNEL];        // 32 KB
    __shared__ float att_s[EB][N_REL];          // 15.9 KB
    __shared__ float rw_s[N_REL][CHANNEL + 1];  // padded: (r+c)%32 banks in precompute
    __shared__ int   cnt_s[EB];
    const int tid = threadIdx.x, lane = tid & 63, wib = tid >> 6; // 8 waves
    const int cb = blockIdx.x, h0 = cb * EB;

    for (int i = tid; i < EB * CHANNEL; i += 512) accum[i >> 6][i & 63] = 0.f;
    for (int i = tid; i < N_REL * CHANNEL; i += 512) rw_s[i >> 6][i & 63] = rel_w[i];
    if (tid < EB) cnt_s[tid] = 0;
    __syncthreads();

    // att[hl][r] = sigmoid(dot(emb[h0+hl], rel_w[r])); each pair once per bucket
    for (int p = tid; p < EB * N_REL; p += 512) {
        const int hl = p / N_REL, r = p % N_REL;
        const int h = h0 + hl;
        float a = 0.f;
        if (h < N_ENTITIES) {
            const float* row = &emb[(size_t)h * CHANNEL];
            #pragma unroll 8
            for (int c = 0; c < CHANNEL; ++c) a += row[c] * rw_s[r][c];
            a = 1.f / (1.f + __expf(-a));
        }
        att_s[hl][r] = a;
    }
    __syncthreads();

    const int bstart = baseE[cb], bend = baseE[cb + 1];
    for (int b0 = bstart + wib * 64; b0 < bend; b0 += 8 * 64) {
        const int idx = b0 + lane;
        const int pl = (idx < bend) ? payE[idx] : 0;
        const int nj = min(64, bend - b0);
        #pragma unroll 4
        for (int j = 0; j < nj; ++j) {
            const int p  = __shfl(pl, j);
            const int hl = (p >> 22) & 127, r = (p >> 17) & 31, t = p & 0x1FFFF;
            const float v = att_s[hl][r] * rw_s[r][lane] *
                            emb[(size_t)t * CHANNEL + lane];
            atomicAdd(&accum[hl][lane], v);
            if (lane == j) atomicAdd(&cnt_s[hl], 1);
        }
    }
    __syncthreads();
    for (int hl = wib; hl < EB; hl += 8) {
        const int h = h0 + hl;
        if (h < N_ENTITIES)
            out_ent[(size_t)h * CHANNEL + lane] =
                accum[hl][lane] / fmaxf((float)cnt_s[hl], 1.f);
    }
}

// One block per 128-user bucket; SpMM accumulate in LDS + gating epilogue.
__global__ __launch_bounds__(512) void user_agg_kernel(
        const float* __restrict__ emb, const float* __restrict__ user_emb,
        const float* __restrict__ latent, const float* __restrict__ weight,
        const float* __restrict__ datt,
        const int* __restrict__ baseU, const int2* __restrict__ payU,
        float* __restrict__ out_user) {
    __shared__ float accum[UB][CHANNEL];        // 32 KB
    __shared__ float dw[4][CHANNEL];
    const int tid = threadIdx.x, lane = tid & 63, wib = tid >> 6;
    const int cb = blockIdx.x, u0 = cb * UB;

    for (int i = tid; i < UB * CHANNEL; i += 512) accum[i >> 6][i & 63] = 0.f;
    if (tid < 256) {   // disen_weight = softmax(datt) @ weight
        const int f = tid >> 6, c = tid & 63;
        float mx = -1e30f;
        for (int j = 0; j < N_META; ++j) mx = fmaxf(mx, datt[f * N_META + j]);
        float s = 0.f, acc = 0.f;
        for (int j = 0; j < N_META; ++j) {
            const float pj = __expf(datt[f * N_META + j] - mx);
            s += pj; acc += pj * weight[j * CHANNEL + c];
        }
        dw[f][c] = acc / s;
    }
    __syncthreads();

    const int bstart = baseU[cb], bend = baseU[cb + 1];
    for (int b0 = bstart + wib * 64; b0 < bend; b0 += 8 * 64) {
        const int idx = b0 + lane;
        int2 pl = make_int2(0, 0);
        if (idx < bend) pl = payU[idx];
        const int nj = min(64, bend - b0);
        #pragma unroll 4
        for (int j = 0; j < nj; ++j) {
            const int w0 = __shfl(pl.x, j), w1 = __shfl(pl.y, j);
            const int ul = (w0 >> 17) & 127, c = w0 & 0x1FFFF;
            atomicAdd(&accum[ul][lane],
                      __int_as_float(w1) * emb[(size_t)c * CHANNEL + lane]);
        }
    }
    __syncthreads();
    for (int ul = wib; ul < UB; ul += 8) {
        const int u = u0 + ul;
        if (u < N_USERS) {
            const float ue = user_emb[(size_t)u * CHANNEL + lane];
            float d0 = wave_reduce_sum(ue * latent[0 * CHANNEL + lane]);
            float d1 = wave_reduce_sum(ue * latent[1 * CHANNEL + lane]);
            float d2 = wave_reduce_sum(ue * latent[2 * CHANNEL + lane]);
            float d3 = wave_reduce_sum(ue * latent[3 * CHANNEL + lane]);
            const float mx = fmaxf(fmaxf(d0, d1), fmaxf(d2, d3));
            d0 = __expf(d0 - mx); d1 = __expf(d1 - mx);
            d2 = __expf(d2 - mx); d3 = __expf(d3 - mx);
            const float invs = 1.f / (d0 + d1 + d2 + d3);
            const float g = (d0 * dw[0][lane] + d1 * dw[1][lane] +
                             d2 * dw[2][lane] + d3 * dw[3][lane]) * invs;
            out_user[(size_t)u * CHANNEL + lane] = accum[ul][lane] * (1.f + g);
        }
    }
}

extern "C" void kernel_launch(void* const* d_in, const int* in_sizes, int n_in,
                              void* d_out, int out_size, void* d_ws, size_t ws_size,
                              hipStream_t stream) {
    const float* entity_emb = (const float*)d_in[0];
    const float* user_emb   = (const float*)d_in[1];
    const float* latent_emb = (const float*)d_in[2];
    const int*   head       = (const int*)d_in[3];
    const int*   tail       = (const int*)d_in[4];
    const int*   etype      = (const int*)d_in[5];
    const int*   mat_row    = (const int*)d_in[6];
    const int*   mat_col    = (const int*)d_in[7];
    const float* mat_val    = (const float*)d_in[8];
    const float* rel_w      = (const float*)d_in[9];
    const float* weight     = (const float*)d_in[10];
    const float* datt       = (const float*)d_in[11];

    float* out      = (float*)d_out;
    float* out_ent  = out;                                  // N_ENTITIES*64
    float* out_user = out + (size_t)N_ENTITIES * CHANNEL;   // N_USERS*64

    int*  ws    = (int*)d_ws;
    int*  cntE  = ws;             // 782 (pad 800)
    int*  cntU  = ws + 800;       // 391 (pad 400)
    int*  baseE = ws + 1200;      // 783 (pad 800)
    int*  baseU = ws + 2000;      // 392 (pad 400)
    int*  curE  = ws + 2400;      // 782 (pad 800)
    int*  curU  = ws + 3200;      // 391 (pad 400)
    int*  payE  = ws + 3600;      // 1.6M
    int2* payU  = (int2*)(ws + 1603600); // 1M int2 (8B-aligned)

    hipMemsetAsync(ws, 0, 1200 * sizeof(int), stream);   // cntE + cntU

    count_kernel<<<256, 256, 0, stream>>>(head, mat_row, cntE, cntU);
    scan_kernel<<<1, 1024, 0, stream>>>(cntE, cntU, baseE, curE, baseU, curU);
    scatter_kernel<<<ETILES + NTILES, 256, 0, stream>>>(head, tail, etype,
                                                        mat_row, mat_col, mat_val,
                                                        curE, curU, payE, payU);
    ent_agg_kernel<<<NB_E, 512, 0, stream>>>(entity_emb, rel_w, baseE, payE, out_ent);
    user_agg_kernel<<<NB_U, 512, 0, stream>>>(entity_emb, user_emb, latent_emb,
                                              weight, datt, baseU, payU, out_user);
}

// Round 6
// 1366.957 us; speedup vs baseline: 1.1548x; 1.0468x over previous
//
#include <hip/hip_runtime.h>

constexpr int N_ENTITIES = 100000;
constexpr int N_USERS    = 50000;
constexpr int N_META     = 8;
constexpr int CHANNEL    = 64;
constexpr int N_EDGES    = 1600000;
constexpr int NNZ        = 1000000;
constexpr int N_REL      = 31;

constexpr int EB   = 64;                               // heads per entity bucket
constexpr int UB   = 64;                               // users per user bucket
constexpr int NB_E = (N_ENTITIES + EB - 1) / EB;       // 1563
constexpr int NB_U = (N_USERS + UB - 1) / UB;          // 782
constexpr int TILE   = 8192;
constexpr int ETILES = (N_EDGES + TILE - 1) / TILE;    // 196
constexpr int NTILES = (NNZ + TILE - 1) / TILE;        // 123

// ws ints: cntH@0(100000) cntU@100000(800) baseE@100800(1600) baseU@102400(800)
//          curE@103200(1600) curU@104800(800) payE@105600(1.6M) payU@1705600(2M)

__device__ __forceinline__ float wave_reduce_sum(float v) {
    for (int off = 32; off > 0; off >>= 1)
        v += __shfl_xor(v, off, 64);
    return v;
}

__global__ void count_kernel(const int* __restrict__ head,
                             const int* __restrict__ mat_row,
                             int* __restrict__ cntH,      // per-head, global
                             int* __restrict__ cntU) {    // per-user-bucket
    __shared__ int hu[NB_U];
    for (int i = threadIdx.x; i < NB_U; i += blockDim.x) hu[i] = 0;
    __syncthreads();
    const int i0 = blockIdx.x * blockDim.x + threadIdx.x;
    const int st = gridDim.x * blockDim.x;
    for (int e = i0; e < N_EDGES; e += st) atomicAdd(&cntH[head[e]], 1);
    for (int z = i0; z < NNZ;     z += st) atomicAdd(&hu[mat_row[z] >> 6], 1);
    __syncthreads();
    for (int i = threadIdx.x; i < NB_U; i += blockDim.x)
        if (hu[i]) atomicAdd(&cntU[i], hu[i]);
}

__device__ __forceinline__ void block_scan_1024(int* arr) {
    const int t = threadIdx.x;
    for (int d = 1; d < 1024; d <<= 1) {
        const int v = (t >= d) ? arr[t - d] : 0;
        __syncthreads();
        arr[t] += v;
        __syncthreads();
    }
}

__global__ void scan_kernel(const int* __restrict__ cntH,
                            const int* __restrict__ cntU,
                            int* __restrict__ baseE, int* __restrict__ curE,
                            int* __restrict__ baseU, int* __restrict__ curU) {
    __shared__ int arr[1024];
    const int t = threadIdx.x;
    if (blockIdx.x == 0) {
        // entity buckets: thread t covers buckets 2t, 2t+1 (2048 >= 1563)
        const int b0 = 2 * t, b1 = 2 * t + 1;
        int c0 = 0, c1 = 0;
        if (b0 < NB_E) {
            const int hend = min(b0 * EB + EB, N_ENTITIES);
            for (int h = b0 * EB; h < hend; ++h) c0 += cntH[h];
        }
        if (b1 < NB_E) {
            const int hend = min(b1 * EB + EB, N_ENTITIES);
            for (int h = b1 * EB; h < hend; ++h) c1 += cntH[h];
        }
        arr[t] = c0 + c1;
        __syncthreads();
        block_scan_1024(arr);
        const int excl = t ? arr[t - 1] : 0;
        if (b0 < NB_E) { baseE[b0] = excl;      curE[b0] = excl; }
        if (b1 < NB_E) { baseE[b1] = excl + c0; curE[b1] = excl + c0; }
        if (t == 1023) baseE[NB_E] = arr[1023];
    } else {
        const int own = (t < NB_U) ? cntU[t] : 0;
        arr[t] = own;
        __syncthreads();
        block_scan_1024(arr);
        if (t < NB_U) { const int e = arr[t] - own; baseU[t] = e; curU[t] = e; }
        if (t == 1023) baseU[NB_U] = arr[1023];
    }
}

__global__ void scatter_kernel(const int* __restrict__ head,
                               const int* __restrict__ tail,
                               const int* __restrict__ etype,
                               const int* __restrict__ mat_row,
                               const int* __restrict__ mat_col,
                               const float* __restrict__ mat_val,
                               int* __restrict__ curE, int* __restrict__ curU,
                               int* __restrict__ payE, int2* __restrict__ payU) {
    __shared__ int hist[NB_E], bbase[NB_E], lcur[NB_E];
    const int tid = threadIdx.x;
    if (blockIdx.x < ETILES) {
        for (int i = tid; i < NB_E; i += blockDim.x) { hist[i] = 0; lcur[i] = 0; }
        __syncthreads();
        const int s = blockIdx.x * TILE, e = min(s + TILE, N_EDGES);
        for (int i = s + tid; i < e; i += blockDim.x) atomicAdd(&hist[head[i] >> 6], 1);
        __syncthreads();
        for (int b = tid; b < NB_E; b += blockDim.x)
            if (hist[b]) bbase[b] = atomicAdd(&curE[b], hist[b]);
        __syncthreads();
        for (int i = s + tid; i < e; i += blockDim.x) {
            const int h = head[i], b = h >> 6;
            const int pos = atomicAdd(&lcur[b], 1);
            payE[bbase[b] + pos] = ((h & 63) << 22) | ((etype[i] - 1) << 17) | tail[i];
        }
    } else {
        for (int i = tid; i < NB_U; i += blockDim.x) { hist[i] = 0; lcur[i] = 0; }
        __syncthreads();
        const int s = (blockIdx.x - ETILES) * TILE, e = min(s + TILE, NNZ);
        for (int i = s + tid; i < e; i += blockDim.x) atomicAdd(&hist[mat_row[i] >> 6], 1);
        __syncthreads();
        for (int b = tid; b < NB_U; b += blockDim.x)
            if (hist[b]) bbase[b] = atomicAdd(&curU[b], hist[b]);
        __syncthreads();
        for (int i = s + tid; i < e; i += blockDim.x) {
            const int r = mat_row[i], b = r >> 6;
            const int pos = atomicAdd(&lcur[b], 1);
            int2 p; p.x = ((r & 63) << 17) | mat_col[i]; p.y = __float_as_int(mat_val[i]);
            payU[bbase[b] + pos] = p;
        }
    }
}

// One block per 64-head bucket. ~32.7 KB LDS -> 4 blocks/CU. Each wave batches
// K=4 edges/iter: 4 independent gathers in flight, then 4 ds_adds. No shfl loop.
__global__ __launch_bounds__(512) void ent_agg_kernel(
        const float* __restrict__ emb, const float* __restrict__ rel_w,
        const int* __restrict__ baseE, const int* __restrict__ cntH,
        const int* __restrict__ payE, float* __restrict__ out_ent) {
    __shared__ float accum[EB][CHANNEL];        // 16 KB
    __shared__ float att_s[EB][32];             // 8 KB
    __shared__ float rw_s[N_REL][CHANNEL + 1];  // 8.06 KB
    const int tid = threadIdx.x, lane = tid & 63, wib = tid >> 6; // 8 waves
    const int cb = blockIdx.x, h0 = cb * EB;

    for (int i = tid; i < EB * CHANNEL; i += 512) accum[i >> 6][i & 63] = 0.f;
    for (int i = tid; i < N_REL * CHANNEL; i += 512)
        rw_s[i >> 6][i & 63] = rel_w[i];
    __syncthreads();

    // att[hl][r] = sigmoid(dot(emb[h0+hl], rel_w[r])), each pair once
    for (int p = tid; p < EB * N_REL; p += 512) {
        const int hl = p / N_REL, r = p % N_REL;
        const int h = h0 + hl;
        float a = 0.f;
        if (h < N_ENTITIES) {
            const float* row = &emb[(size_t)h * CHANNEL];
            #pragma unroll 8
            for (int c = 0; c < CHANNEL; ++c) a += row[c] * rw_s[r][c];
            a = 1.f / (1.f + __expf(-a));
        }
        att_s[hl][r] = a;
    }
    __syncthreads();

    const int bstart = baseE[cb], bend = baseE[cb + 1];
    for (int i0 = bstart + wib * 4; i0 < bend; i0 += 32) {
        int pls[4];
        #pragma unroll
        for (int k = 0; k < 4; ++k) {
            const int idx = i0 + k;
            pls[k] = (idx < bend) ? payE[idx] : -1;
        }
        float gv[4]; int hls[4];
        #pragma unroll
        for (int k = 0; k < 4; ++k) {
            if (pls[k] >= 0) {
                const int p = pls[k];
                hls[k] = (p >> 22) & 63;
                const int r = (p >> 17) & 31, t = p & 0x1FFFF;
                gv[k] = att_s[hls[k]][r] * rw_s[r][lane] *
                        emb[(size_t)t * CHANNEL + lane];
            }
        }
        #pragma unroll
        for (int k = 0; k < 4; ++k)
            if (pls[k] >= 0) atomicAdd(&accum[hls[k]][lane], gv[k]);
    }
    __syncthreads();

    for (int hl = wib; hl < EB; hl += 8) {
        const int h = h0 + hl;
        if (h < N_ENTITIES)
            out_ent[(size_t)h * CHANNEL + lane] =
                accum[hl][lane] / fmaxf((float)cntH[h], 1.f);
    }
}

// One block per 64-user bucket; 17 KB LDS; same K=4 batching; gating fused.
__global__ __launch_bounds__(512) void user_agg_kernel(
        const float* __restrict__ emb, const float* __restrict__ user_emb,
        const float* __restrict__ latent, const float* __restrict__ weight,
        const float* __restrict__ datt,
        const int* __restrict__ baseU, const int2* __restrict__ payU,
        float* __restrict__ out_user) {
    __shared__ float accum[UB][CHANNEL];        // 16 KB
    __shared__ float dw[4][CHANNEL];            // 1 KB
    const int tid = threadIdx.x, lane = tid & 63, wib = tid >> 6;
    const int cb = blockIdx.x, u0 = cb * UB;

    for (int i = tid; i < UB * CHANNEL; i += 512) accum[i >> 6][i & 63] = 0.f;
    if (tid < 256) {   // disen_weight = softmax(datt) @ weight
        const int f = tid >> 6, c = tid & 63;
        float mx = -1e30f;
        for (int j = 0; j < N_META; ++j) mx = fmaxf(mx, datt[f * N_META + j]);
        float s = 0.f, acc = 0.f;
        for (int j = 0; j < N_META; ++j) {
            const float pj = __expf(datt[f * N_META + j] - mx);
            s += pj; acc += pj * weight[j * CHANNEL + c];
        }
        dw[f][c] = acc / s;
    }
    __syncthreads();

    const int bstart = baseU[cb], bend = baseU[cb + 1];
    for (int i0 = bstart + wib * 4; i0 < bend; i0 += 32) {
        int px[4], py[4];
        #pragma unroll
        for (int k = 0; k < 4; ++k) {
            const int idx = i0 + k;
            if (idx < bend) { const int2 p = payU[idx]; px[k] = p.x; py[k] = p.y; }
            else px[k] = -1;
        }
        float gv[4]; int uls[4];
        #pragma unroll
        for (int k = 0; k < 4; ++k) {
            if (px[k] >= 0) {
                uls[k] = (px[k] >> 17) & 63;
                const int c = px[k] & 0x1FFFF;
                gv[k] = __int_as_float(py[k]) * emb[(size_t)c * CHANNEL + lane];
            }
        }
        #pragma unroll
        for (int k = 0; k < 4; ++k)
            if (px[k] >= 0) atomicAdd(&accum[uls[k]][lane], gv[k]);
    }
    __syncthreads();

    for (int ul = wib; ul < UB; ul += 8) {
        const int u = u0 + ul;
        if (u < N_USERS) {
            const float ue = user_emb[(size_t)u * CHANNEL + lane];
            float d0 = wave_reduce_sum(ue * latent[0 * CHANNEL + lane]);
            float d1 = wave_reduce_sum(ue * latent[1 * CHANNEL + lane]);
            float d2 = wave_reduce_sum(ue * latent[2 * CHANNEL + lane]);
            float d3 = wave_reduce_sum(ue * latent[3 * CHANNEL + lane]);
            const float mx = fmaxf(fmaxf(d0, d1), fmaxf(d2, d3));
            d0 = __expf(d0 - mx); d1 = __expf(d1 - mx);
            d2 = __expf(d2 - mx); d3 = __expf(d3 - mx);
            const float invs = 1.f / (d0 + d1 + d2 + d3);
            const float g = (d0 * dw[0][lane] + d1 * dw[1][lane] +
                             d2 * dw[2][lane] + d3 * dw[3][lane]) * invs;
            out_user[(size_t)u * CHANNEL + lane] = accum[ul][lane] * (1.f + g);
        }
    }
}

extern "C" void kernel_launch(void* const* d_in, const int* in_sizes, int n_in,
                              void* d_out, int out_size, void* d_ws, size_t ws_size,
                              hipStream_t stream) {
    const float* entity_emb = (const float*)d_in[0];
    const float* user_emb   = (const float*)d_in[1];
    const float* latent_emb = (const float*)d_in[2];
    const int*   head       = (const int*)d_in[3];
    const int*   tail       = (const int*)d_in[4];
    const int*   etype      = (const int*)d_in[5];
    const int*   mat_row    = (const int*)d_in[6];
    const int*   mat_col    = (const int*)d_in[7];
    const float* mat_val    = (const float*)d_in[8];
    const float* rel_w      = (const float*)d_in[9];
    const float* weight     = (const float*)d_in[10];
    const float* datt       = (const float*)d_in[11];

    float* out      = (float*)d_out;
    float* out_ent  = out;                                  // N_ENTITIES*64
    float* out_user = out + (size_t)N_ENTITIES * CHANNEL;   // N_USERS*64

    int*  ws    = (int*)d_ws;
    int*  cntH  = ws;               // 100000
    int*  cntU  = ws + 100000;      // 782 (pad 800)
    int*  baseE = ws + 100800;      // 1564 (pad 1600)
    int*  baseU = ws + 102400;      // 783 (pad 800)
    int*  curE  = ws + 103200;      // 1563 (pad 1600)
    int*  curU  = ws + 104800;      // 782 (pad 800)
    int*  payE  = ws + 105600;      // 1.6M
    int2* payU  = (int2*)(ws + 1705600);  // 1M int2, 8B-aligned

    hipMemsetAsync(ws, 0, 100800 * sizeof(int), stream);   // cntH + cntU

    count_kernel<<<512, 256, 0, stream>>>(head, mat_row, cntH, cntU);
    scan_kernel<<<2, 1024, 0, stream>>>(cntH, cntU, baseE, curE, baseU, curU);
    scatter_kernel<<<ETILES + NTILES, 256, 0, stream>>>(head, tail, etype,
                                                        mat_row, mat_col, mat_val,
                                                        curE, curU, payE, payU);
    ent_agg_kernel<<<NB_E, 512, 0, stream>>>(entity_emb, rel_w, baseE, cntH,
                                             payE, out_ent);
    user_agg_kernel<<<NB_U, 512, 0, stream>>>(entity_emb, user_emb, latent_emb,
                                              weight, datt, baseU, payU, out_user);
}